// Round 17
// baseline (182.920 us; speedup 1.0000x reference)
//
#include <hip/hip_runtime.h>
#include <stdint.h>

#define NTOK 65536
#define CAP 16384

typedef unsigned int u32;
typedef unsigned short u16;
typedef short short8 __attribute__((ext_vector_type(8)));   // 8 bf16 bit-patterns (MFMA frag)
typedef float f32x4 __attribute__((ext_vector_type(4)));

// ---- ws layout ----
#define MW_W1F   0u           // 1MB fragment-major W1
#define MW_W2F   1048576u     // 1MB fragment-major W2
#define MW_REC   2097152u     // 65536 x uint4
#define MW_PRW   3145728u     // 131072 x uint2 {exRow|~0, gateBits}
#define MW_CNT   4194304u     // 8 x int
#define MW_BCNT  4202496u     // 256 x 8 u32
#define MW_BBASE 4210688u     // 256 x 8 u32
#define MW_IDX   5242880u     // 8 x CAP x uint2 {pair, gateBits}
#define MW_W1T   6291456u     // atomic tier
#define MW_W2T   7340032u
#define WS_ATOM  8388608u
#define MW_YBUF  8388608u     // 131072 x 512B bf16 rows, indexed by PAIR
#define WS_FAST  75497472u

__device__ __forceinline__ u16 f2bf(float f) {
  __bf16 h = (__bf16)f;                       // native RNE cast (v_cvt)
  u16 u; __builtin_memcpy(&u, &h, 2); return u;
}
__device__ __forceinline__ float bfbits(u32 b16) {
  u32 x = b16 << 16; float f; __builtin_memcpy(&f, &x, 4); return f;
}
__device__ __forceinline__ f32x4 zero4() {
  f32x4 z; z[0] = 0.f; z[1] = 0.f; z[2] = 0.f; z[3] = 0.f; return z;
}

// ---- P: pack W into fragment-major layout ----
__global__ __launch_bounds__(64) void k_pack(
    const float* __restrict__ W1, const float* __restrict__ W2,
    u16* __restrict__ W1F, u16* __restrict__ W2F) {
  int lane = threadIdx.x;
  int chunk = blockIdx.x;            // ks*16 + ntile
  int e = blockIdx.y;
  const float* S = (blockIdx.z ? W2 : W1) + ((size_t)e << 16);
  u16* D = (blockIdx.z ? W2F : W1F) + (((size_t)e * 128 + chunk) * 64 + lane) * 8;
  int ks = chunk >> 4, ntile = chunk & 15;
  int lg = lane >> 4, lc = lane & 15;
  int n = ntile * 16 + lc;
  int k0 = ks * 32 + lg * 8;
  u16 v[8];
  #pragma unroll
  for (int j = 0; j < 8; ++j) v[j] = f2bf(S[(size_t)(k0 + j) * 256 + n]);
  uint4 pk;
  pk.x = (u32)v[0] | ((u32)v[1] << 16);
  pk.y = (u32)v[2] | ((u32)v[3] << 16);
  pk.z = (u32)v[4] | ((u32)v[5] << 16);
  pk.w = (u32)v[6] | ((u32)v[7] << 16);
  *reinterpret_cast<uint4*>(D) = pk;
}

// ---- T: transpose (atomic tier only) ----
__global__ __launch_bounds__(256) void k_transpose(
    const float* __restrict__ W1, const float* __restrict__ W2,
    u16* __restrict__ W1T, u16* __restrict__ W2T) {
  __shared__ u16 t[32][33];
  int tile = blockIdx.x, e = blockIdx.y;
  const float* S = (blockIdx.z ? W2 : W1) + (size_t)e * 65536;
  u16* D = (blockIdx.z ? W2T : W1T) + (size_t)e * 65536;
  int r0 = (tile >> 3) * 32, c0 = (tile & 7) * 32;
  int tr = threadIdx.x >> 5, tc = threadIdx.x & 31;
  #pragma unroll
  for (int i = 0; i < 32; i += 8) t[tr + i][tc] = f2bf(S[(size_t)(r0 + tr + i) * 256 + c0 + tc]);
  __syncthreads();
  #pragma unroll
  for (int i = 0; i < 32; i += 8) D[(size_t)(c0 + tr + i) * 256 + r0 + tc] = t[tc][tr + i];
}

// ---- R: router (f64, top-2, softmax) ----
__global__ __launch_bounds__(256) void k_router_f(
    const float* __restrict__ x0, const float* __restrict__ Wr, const float* __restrict__ br,
    uint4* __restrict__ recAll) {
  __shared__ double sWr[256][8];
  __shared__ double sbr[8];
  int tid = threadIdx.x;
  #pragma unroll
  for (int e = 0; e < 8; ++e) sWr[tid][e] = (double)Wr[tid * 8 + e];
  if (tid < 8) sbr[tid] = (double)br[tid];
  __syncthreads();
  int t = blockIdx.x * 256 + tid;
  const float* xr = x0 + (size_t)t * 256;
  double acc[8];
  #pragma unroll
  for (int e = 0; e < 8; ++e) acc[e] = sbr[e];
  for (int dc = 0; dc < 256; dc += 4) {
    float4 xv = *reinterpret_cast<const float4*>(xr + dc);
    double xd[4] = {(double)xv.x, (double)xv.y, (double)xv.z, (double)xv.w};
    #pragma unroll
    for (int q = 0; q < 4; ++q)
      #pragma unroll
      for (int e = 0; e < 8; ++e) acc[e] += xd[q] * sWr[dc + q][e];
  }
  double v0 = -1e300, v1 = -1e300; int e0 = 0, e1 = 0;
  #pragma unroll
  for (int e = 0; e < 8; ++e) {
    double v = acc[e];
    if (v > v0) { v1 = v0; e1 = e0; v0 = v; e0 = e; }
    else if (v > v1) { v1 = v; e1 = e; }
  }
  double tt = exp(v1 - v0);
  double inv = 1.0 / (1.0 + tt);
  float g0 = (float)inv, g1 = (float)(tt * inv);
  uint4 rec;
  __builtin_memcpy(&rec.x, &g0, 4);
  __builtin_memcpy(&rec.y, &g1, 4);
  rec.z = (u32)e0 | ((u32)e1 << 8);
  rec.w = 0u;
  recAll[t] = rec;
}

// ---- S1: per-block expert histogram ----
__global__ __launch_bounds__(256) void k_count(
    const uint4* __restrict__ recAll, u32* __restrict__ blkCnt) {
  __shared__ u32 hist[8];
  int tid = threadIdx.x;
  if (tid < 8) hist[tid] = 0;
  __syncthreads();
  uint4 rec = recAll[blockIdx.x * 256 + tid];
  atomicAdd(&hist[rec.z & 255], 1u);
  atomicAdd(&hist[(rec.z >> 8) & 255], 1u);
  __syncthreads();
  if (tid < 8) blkCnt[blockIdx.x * 8 + tid] = hist[tid];
}

// ---- S2: exclusive scan of block-counts per expert ----
__global__ __launch_bounds__(256) void k_offset(
    const u32* __restrict__ blkCnt, u32* __restrict__ blkBase, int* __restrict__ cntE) {
  __shared__ u32 s[2048];
  int tid = threadIdx.x;
  #pragma unroll
  for (int i = 0; i < 8; ++i) s[tid + i * 256] = blkCnt[tid + i * 256];
  __syncthreads();
  if (tid < 8) {
    u32 run = 0;
    for (int b = 0; b < 256; ++b) {
      u32 v = s[b * 8 + tid];
      s[b * 8 + tid] = run;
      run += v;
    }
    cntE[tid] = (int)(run < (u32)CAP ? run : (u32)CAP);
  }
  __syncthreads();
  #pragma unroll
  for (int i = 0; i < 8; ++i) blkBase[tid + i * 256] = s[tid + i * 256];
}

// ---- S3: place pairs in exact global order -> idx lists + pairRW ----
__global__ __launch_bounds__(256) void k_place(
    const uint4* __restrict__ recAll, const u32* __restrict__ blkBase,
    uint2* __restrict__ idx, uint2* __restrict__ pairRW) {
  __shared__ u32 wavetot[4][8];
  __shared__ u32 wavebase[4][8];
  int tid = threadIdx.x;
  int lane = tid & 63, w = tid >> 6;
  int t = blockIdx.x * 256 + tid;
  uint4 rec = recAll[t];
  int e0 = rec.z & 255, e1 = (rec.z >> 8) & 255;
  u32 c[8];
  #pragma unroll
  for (int j = 0; j < 8; ++j) c[j] = (u32)(e0 == j) + (u32)(e1 == j);
  u32 inc[8];
  #pragma unroll
  for (int j = 0; j < 8; ++j) inc[j] = c[j];
  for (int d = 1; d < 64; d <<= 1) {
    #pragma unroll
    for (int j = 0; j < 8; ++j) {
      u32 n = __shfl_up(inc[j], d);
      if (lane >= d) inc[j] += n;
    }
  }
  if (lane == 63) {
    #pragma unroll
    for (int j = 0; j < 8; ++j) wavetot[w][j] = inc[j];
  }
  __syncthreads();
  if (tid < 8) {
    u32 run = 0;
    for (int ww = 0; ww < 4; ++ww) { wavebase[ww][tid] = run; run += wavetot[ww][tid]; }
  }
  __syncthreads();
  u32 run[8];
  #pragma unroll
  for (int j = 0; j < 8; ++j)
    run[j] = blkBase[blockIdx.x * 8 + j] + wavebase[w][j] + inc[j] - c[j];
  u32 p0 = run[e0]++;
  u32 p1 = run[e1]++;
  uint2 rw0, rw1;
  if (p0 < (u32)CAP) { idx[(u32)e0 * CAP + p0] = make_uint2((u32)(2 * t), rec.x); rw0 = make_uint2((u32)e0 * CAP + p0, rec.x); }
  else rw0 = make_uint2(0xFFFFFFFFu, 0u);
  if (p1 < (u32)CAP) { idx[(u32)e1 * CAP + p1] = make_uint2((u32)(2 * t + 1), rec.y); rw1 = make_uint2((u32)e1 * CAP + p1, rec.y); }
  else rw1 = make_uint2(0xFFFFFFFFu, 0u);
  pairRW[2 * t] = rw0;
  pairRW[2 * t + 1] = rw1;
}

// ---- E_g: expert MLP; f32-gather A (native-cast pack), frag-major B, LDS-staged y writes ----
__global__ __launch_bounds__(512, 4) void k_expert_g(
    const float* __restrict__ x0,
    const u16* __restrict__ W1F, const float* __restrict__ b1,
    const float* __restrict__ ln1s, const float* __restrict__ ln1b,
    const u16* __restrict__ W2F, const float* __restrict__ b2,
    const float* __restrict__ ln2s, const float* __restrict__ ln2b,
    const uint2* __restrict__ idx2, const int* __restrict__ cntE,
    u16* __restrict__ ybuf) {
  __shared__ __attribute__((aligned(16))) char sm[32768];
  __shared__ float red[512];     // [64][4][2]
  __shared__ float musig[128];   // [64][2]
  __shared__ int pArr[64];

  const int e = blockIdx.y;
  const int cnt = cntE[e];
  const int rblk = blockIdx.x * 64;
  if (rblk >= cnt) return;

  const int tid = threadIdx.x;
  const int w = tid >> 6, lane = tid & 63;
  const int wr = w >> 2, wc = w & 3;
  const int lg = lane >> 4, lc = lane & 15;
  const int ncol = wc * 64 + lc;

  // gather 64 rows (f32 -> bf16 native cast), XOR-swizzled 16B slots (slot ^= row&7)
  #pragma unroll
  for (int it = 0; it < 4; ++it) {
    int id = tid + it * 512;
    int row = id >> 5, s = id & 31;
    int r = rblk + row;
    uint2 en = make_uint2(0u, 0u);
    if (r < cnt) en = idx2[e * CAP + r];
    if (s == 0) pArr[row] = (int)en.x;
    int tok = (int)(en.x >> 1);
    int ssrc = s ^ (row & 7);
    const float* src = x0 + (size_t)tok * 256 + ssrc * 8;
    float4 f0 = *reinterpret_cast<const float4*>(src);
    float4 f1 = *reinterpret_cast<const float4*>(src + 4);
    uint4 pk;
    pk.x = (u32)f2bf(f0.x) | ((u32)f2bf(f0.y) << 16);
    pk.y = (u32)f2bf(f0.z) | ((u32)f2bf(f0.w) << 16);
    pk.z = (u32)f2bf(f1.x) | ((u32)f2bf(f1.y) << 16);
    pk.w = (u32)f2bf(f1.z) | ((u32)f2bf(f1.w) << 16);
    *reinterpret_cast<uint4*>(sm + row * 512 + s * 16) = pk;
  }
  __syncthreads();

  f32x4 acc[2][4];
  const u16* BF1 = W1F + (size_t)e * 128 * 64 * 8;
  const u16* BF2 = W2F + (size_t)e * 128 * 64 * 8;

#define GEMM(BF) do { \
    _Pragma("unroll") \
    for (int ks = 0; ks < 8; ++ks) { \
      short8 bfr[4]; \
      _Pragma("unroll") \
      for (int nt = 0; nt < 4; ++nt) \
        bfr[nt] = *reinterpret_cast<const short8*>((BF) + (((ks * 16) + wc * 4 + nt) * 64 + lane) * 8); \
      short8 afr[2]; \
      _Pragma("unroll") \
      for (int mt = 0; mt < 2; ++mt) { \
        int row = wr * 32 + mt * 16 + lc; \
        int slot = (ks * 4 + lg) ^ (row & 7); \
        afr[mt] = *reinterpret_cast<const short8*>(sm + row * 512 + slot * 16); \
      } \
      _Pragma("unroll") \
      for (int mt = 0; mt < 2; ++mt) \
        _Pragma("unroll") \
        for (int nt = 0; nt < 4; ++nt) \
          acc[mt][nt] = __builtin_amdgcn_mfma_f32_16x16x32_bf16(afr[mt], bfr[nt], acc[mt][nt], 0, 0, 0); \
    } \
  } while (0)

  // ---- GEMM1 ----
  #pragma unroll
  for (int mt = 0; mt < 2; ++mt)
    #pragma unroll
    for (int nt = 0; nt < 4; ++nt) acc[mt][nt] = zero4();
  GEMM(BF1);

  // ---- +b1, LN1 stats ----
  float s1v[4], c1v[4];
  {
    #pragma unroll
    for (int nt = 0; nt < 4; ++nt) {
      int n = ncol + nt * 16;
      float b1v = b1[e * 256 + n];
      s1v[nt] = ln1s[e * 256 + n];
      c1v[nt] = ln1b[e * 256 + n];
      #pragma unroll
      for (int mt = 0; mt < 2; ++mt)
        #pragma unroll
        for (int r = 0; r < 4; ++r) acc[mt][nt][r] += b1v;
    }
    #pragma unroll
    for (int mt = 0; mt < 2; ++mt)
      #pragma unroll
      for (int r = 0; r < 4; ++r) {
        float s = 0.f, q = 0.f;
        #pragma unroll
        for (int nt = 0; nt < 4; ++nt) { float v = acc[mt][nt][r]; s += v; q += v * v; }
        #pragma unroll
        for (int d = 1; d < 16; d <<= 1) { s += __shfl_xor(s, d); q += __shfl_xor(q, d); }
        if (lc == 0) {
          int row = wr * 32 + mt * 16 + lg * 4 + r;
          red[(row * 4 + wc) * 2 + 0] = s;
          red[(row * 4 + wc) * 2 + 1] = q;
        }
      }
  }
  __syncthreads();
  if (tid < 64) {
    float S = 0.f, Q = 0.f;
    #pragma unroll
    for (int j = 0; j < 4; ++j) { S += red[(tid * 4 + j) * 2]; Q += red[(tid * 4 + j) * 2 + 1]; }
    float mu = S * (1.f / 256.f);
    float var = fmaxf(Q * (1.f / 256.f) - mu * mu, 0.f);
    musig[tid * 2] = mu;
    musig[tid * 2 + 1] = rsqrtf(var + 1e-6f);
  }
  __syncthreads();

  // ---- LN1 + relu -> H (bf16) back into sm (per-lane u16 swizzled stores) ----
  #pragma unroll
  for (int mt = 0; mt < 2; ++mt)
    #pragma unroll
    for (int r = 0; r < 4; ++r) {
      int row = wr * 32 + mt * 16 + lg * 4 + r;
      float mu = musig[row * 2], rs = musig[row * 2 + 1];
      #pragma unroll
      for (int nt = 0; nt < 4; ++nt) {
        float v = fmaxf((acc[mt][nt][r] - mu) * rs * s1v[nt] + c1v[nt], 0.f);
        int col = ncol + nt * 16;
        int slot = (col >> 3) ^ (row & 7);
        *reinterpret_cast<u16*>(sm + row * 512 + slot * 16 + (col & 7) * 2) = f2bf(v);
      }
    }
  __syncthreads();

  // ---- GEMM2 ----
  #pragma unroll
  for (int mt = 0; mt < 2; ++mt)
    #pragma unroll
    for (int nt = 0; nt < 4; ++nt) acc[mt][nt] = zero4();
  GEMM(BF2);
#undef GEMM

  // ---- +b2, LN2 stats ----
  float s2v[4], c2v[4];
  #pragma unroll
  for (int nt = 0; nt < 4; ++nt) {
    int n = ncol + nt * 16;
    float b2v = b2[e * 256 + n];
    s2v[nt] = ln2s[e * 256 + n];
    c2v[nt] = ln2b[e * 256 + n];
    #pragma unroll
    for (int mt = 0; mt < 2; ++mt)
      #pragma unroll
      for (int r = 0; r < 4; ++r) acc[mt][nt][r] += b2v;
  }
  __syncthreads();
  #pragma unroll
  for (int mt = 0; mt < 2; ++mt)
    #pragma unroll
    for (int r = 0; r < 4; ++r) {
      float s = 0.f, q = 0.f;
      #pragma unroll
      for (int nt = 0; nt < 4; ++nt) { float v = acc[mt][nt][r]; s += v; q += v * v; }
      #pragma unroll
      for (int d = 1; d < 16; d <<= 1) { s += __shfl_xor(s, d); q += __shfl_xor(q, d); }
      if (lc == 0) {
        int row = wr * 32 + mt * 16 + lg * 4 + r;
        red[(row * 4 + wc) * 2 + 0] = s;
        red[(row * 4 + wc) * 2 + 1] = q;
      }
    }
  __syncthreads();
  if (tid < 64) {
    float S = 0.f, Q = 0.f;
    #pragma unroll
    for (int j = 0; j < 4; ++j) { S += red[(tid * 4 + j) * 2]; Q += red[(tid * 4 + j) * 2 + 1]; }
    float mu = S * (1.f / 256.f);
    float var = fmaxf(Q * (1.f / 256.f) - mu * mu, 0.f);
    musig[tid * 2] = mu;
    musig[tid * 2 + 1] = rsqrtf(var + 1e-6f);
  }
  __syncthreads();

  // ---- LN2 -> y (bf16) into sm (per-lane u16 swizzled stores; sm is dead now) ----
  #pragma unroll
  for (int mt = 0; mt < 2; ++mt)
    #pragma unroll
    for (int r = 0; r < 4; ++r) {
      int row = wr * 32 + mt * 16 + lg * 4 + r;
      float mu = musig[row * 2], rs = musig[row * 2 + 1];
      #pragma unroll
      for (int nt = 0; nt < 4; ++nt) {
        float v = (acc[mt][nt][r] - mu) * rs * s2v[nt] + c2v[nt];
        int col = ncol + nt * 16;
        int slot = (col >> 3) ^ (row & 7);
        *reinterpret_cast<u16*>(sm + row * 512 + slot * 16 + (col & 7) * 2) = f2bf(v);
      }
    }
  __syncthreads();

  // ---- coalesced unswizzling copy LDS -> ybuf[pair] (full 512B bursts per row) ----
  #pragma unroll
  for (int it = 0; it < 4; ++it) {
    int id = tid + it * 512;
    int row = id >> 5, s = id & 31;
    if (rblk + row < cnt) {
      int slot = s ^ (row & 7);
      uint4 v = *reinterpret_cast<const uint4*>(sm + row * 512 + slot * 16);
      int pair = pArr[row];
      *reinterpret_cast<uint4*>((char*)ybuf + (size_t)pair * 512 + s * 16) = v;
    }
  }
}

// ---- E (atomic tier): gather version, gated f32 atomics ----
__global__ __launch_bounds__(512, 4) void k_expert(
    const float* __restrict__ x0,
    const u16* __restrict__ W1T, const float* __restrict__ b1,
    const float* __restrict__ ln1s, const float* __restrict__ ln1b,
    const u16* __restrict__ W2T, const float* __restrict__ b2,
    const float* __restrict__ ln2s, const float* __restrict__ ln2b,
    const uint2* __restrict__ idx2, const int* __restrict__ cntE,
    float* __restrict__ out) {
  __shared__ __attribute__((aligned(16))) char sm[32768];
  __shared__ float red[512];
  __shared__ float musig[128];
  __shared__ int tokArr[64];
  __shared__ float wArr[64];

  const int e = blockIdx.y;
  const int cnt = cntE[e];
  const int rblk = blockIdx.x * 64;
  if (rblk >= cnt) return;

  const int tid = threadIdx.x;
  const int w = tid >> 6, lane = tid & 63;
  const int wr = w >> 2, wc = w & 3;
  const int lg = lane >> 4, lc = lane & 15;

  #pragma unroll
  for (int it = 0; it < 4; ++it) {
    int id = tid + it * 512;
    int row = id >> 5, s = id & 31;
    int r = rblk + row;
    uint2 en = make_uint2(0u, 0u);
    if (r < cnt) en = idx2[e * CAP + r];
    if (s == 0) {
      tokArr[row] = (int)(en.x >> 1);
      float wv; __builtin_memcpy(&wv, &en.y, 4);
      wArr[row] = (r < cnt) ? wv : 0.f;
    }
    int tok = (int)(en.x >> 1);
    int ssrc = s ^ (row & 7);
    const float* src = x0 + (size_t)tok * 256 + ssrc * 8;
    float4 f0 = *reinterpret_cast<const float4*>(src);
    float4 f1 = *reinterpret_cast<const float4*>(src + 4);
    uint4 pk;
    pk.x = (u32)f2bf(f0.x) | ((u32)f2bf(f0.y) << 16);
    pk.y = (u32)f2bf(f0.z) | ((u32)f2bf(f0.w) << 16);
    pk.z = (u32)f2bf(f1.x) | ((u32)f2bf(f1.y) << 16);
    pk.w = (u32)f2bf(f1.z) | ((u32)f2bf(f1.w) << 16);
    *reinterpret_cast<uint4*>(sm + row * 512 + s * 16) = pk;
  }
  __syncthreads();

  f32x4 acc[2][4];
  #pragma unroll
  for (int mt = 0; mt < 2; ++mt)
    #pragma unroll
    for (int nt = 0; nt < 4; ++nt) acc[mt][nt] = zero4();

  {
    const u16* B1 = W1T + ((size_t)e << 16);
    #pragma unroll
    for (int ks = 0; ks < 8; ++ks) {
      short8 bfr[4];
      #pragma unroll
      for (int nt = 0; nt < 4; ++nt) {
        int n = wc * 64 + nt * 16 + lc;
        bfr[nt] = *reinterpret_cast<const short8*>(B1 + n * 256 + ks * 32 + lg * 8);
      }
      short8 afr[2];
      #pragma unroll
      for (int mt = 0; mt < 2; ++mt) {
        int row = wr * 32 + mt * 16 + lc;
        int slot = (ks * 4 + lg) ^ (row & 7);
        afr[mt] = *reinterpret_cast<const short8*>(sm + row * 512 + slot * 16);
      }
      #pragma unroll
      for (int mt = 0; mt < 2; ++mt)
        #pragma unroll
        for (int nt = 0; nt < 4; ++nt)
          acc[mt][nt] = __builtin_amdgcn_mfma_f32_16x16x32_bf16(afr[mt], bfr[nt], acc[mt][nt], 0, 0, 0);
    }
  }

  float s1v[4], c1v[4];
  {
    #pragma unroll
    for (int nt = 0; nt < 4; ++nt) {
      int n = wc * 64 + nt * 16 + lc;
      float b1v = b1[e * 256 + n];
      s1v[nt] = ln1s[e * 256 + n];
      c1v[nt] = ln1b[e * 256 + n];
      #pragma unroll
      for (int mt = 0; mt < 2; ++mt)
        #pragma unroll
        for (int r = 0; r < 4; ++r) acc[mt][nt][r] += b1v;
    }
    #pragma unroll
    for (int mt = 0; mt < 2; ++mt)
      #pragma unroll
      for (int r = 0; r < 4; ++r) {
        float s = 0.f, q = 0.f;
        #pragma unroll
        for (int nt = 0; nt < 4; ++nt) { float v = acc[mt][nt][r]; s += v; q += v * v; }
        #pragma unroll
        for (int d = 1; d < 16; d <<= 1) { s += __shfl_xor(s, d); q += __shfl_xor(q, d); }
        if (lc == 0) {
          int row = wr * 32 + mt * 16 + lg * 4 + r;
          red[(row * 4 + wc) * 2 + 0] = s;
          red[(row * 4 + wc) * 2 + 1] = q;
        }
      }
  }
  __syncthreads();
  if (tid < 64) {
    float S = 0.f, Q = 0.f;
    #pragma unroll
    for (int j = 0; j < 4; ++j) { S += red[(tid * 4 + j) * 2]; Q += red[(tid * 4 + j) * 2 + 1]; }
    float mu = S * (1.f / 256.f);
    float var = fmaxf(Q * (1.f / 256.f) - mu * mu, 0.f);
    musig[tid * 2] = mu;
    musig[tid * 2 + 1] = rsqrtf(var + 1e-6f);
  }
  __syncthreads();

  #pragma unroll
  for (int mt = 0; mt < 2; ++mt)
    #pragma unroll
    for (int r = 0; r < 4; ++r) {
      int row = wr * 32 + mt * 16 + lg * 4 + r;
      float mu = musig[row * 2], rs = musig[row * 2 + 1];
      #pragma unroll
      for (int nt = 0; nt < 4; ++nt) {
        float v = fmaxf((acc[mt][nt][r] - mu) * rs * s1v[nt] + c1v[nt], 0.f);
        int col = wc * 64 + nt * 16 + lc;
        int slot = (col >> 3) ^ (row & 7);
        *reinterpret_cast<u16*>(sm + row * 512 + slot * 16 + (col & 7) * 2) = f2bf(v);
      }
    }
  __syncthreads();

  #pragma unroll
  for (int mt = 0; mt < 2; ++mt)
    #pragma unroll
    for (int nt = 0; nt < 4; ++nt) acc[mt][nt] = zero4();
  {
    const u16* B2 = W2T + ((size_t)e << 16);
    #pragma unroll
    for (int ks = 0; ks < 8; ++ks) {
      short8 bfr[4];
      #pragma unroll
      for (int nt = 0; nt < 4; ++nt) {
        int n = wc * 64 + nt * 16 + lc;
        bfr[nt] = *reinterpret_cast<const short8*>(B2 + n * 256 + ks * 32 + lg * 8);
      }
      short8 afr[2];
      #pragma unroll
      for (int mt = 0; mt < 2; ++mt) {
        int row = wr * 32 + mt * 16 + lc;
        int slot = (ks * 4 + lg) ^ (row & 7);
        afr[mt] = *reinterpret_cast<const short8*>(sm + row * 512 + slot * 16);
      }
      #pragma unroll
      for (int mt = 0; mt < 2; ++mt)
        #pragma unroll
        for (int nt = 0; nt < 4; ++nt)
          acc[mt][nt] = __builtin_amdgcn_mfma_f32_16x16x32_bf16(afr[mt], bfr[nt], acc[mt][nt], 0, 0, 0);
    }
  }

  float s2v[4], c2v[4];
  #pragma unroll
  for (int nt = 0; nt < 4; ++nt) {
    int n = wc * 64 + nt * 16 + lc;
    float b2v = b2[e * 256 + n];
    s2v[nt] = ln2s[e * 256 + n];
    c2v[nt] = ln2b[e * 256 + n];
    #pragma unroll
    for (int mt = 0; mt < 2; ++mt)
      #pragma unroll
      for (int r = 0; r < 4; ++r) acc[mt][nt][r] += b2v;
  }
  __syncthreads();
  #pragma unroll
  for (int mt = 0; mt < 2; ++mt)
    #pragma unroll
    for (int r = 0; r < 4; ++r) {
      float s = 0.f, q = 0.f;
      #pragma unroll
      for (int nt = 0; nt < 4; ++nt) { float v = acc[mt][nt][r]; s += v; q += v * v; }
      #pragma unroll
      for (int d = 1; d < 16; d <<= 1) { s += __shfl_xor(s, d); q += __shfl_xor(q, d); }
      if (lc == 0) {
        int row = wr * 32 + mt * 16 + lg * 4 + r;
        red[(row * 4 + wc) * 2 + 0] = s;
        red[(row * 4 + wc) * 2 + 1] = q;
      }
    }
  __syncthreads();
  if (tid < 64) {
    float S = 0.f, Q = 0.f;
    #pragma unroll
    for (int j = 0; j < 4; ++j) { S += red[(tid * 4 + j) * 2]; Q += red[(tid * 4 + j) * 2 + 1]; }
    float mu = S * (1.f / 256.f);
    float var = fmaxf(Q * (1.f / 256.f) - mu * mu, 0.f);
    musig[tid * 2] = mu;
    musig[tid * 2 + 1] = rsqrtf(var + 1e-6f);
  }
  __syncthreads();

  #pragma unroll
  for (int mt = 0; mt < 2; ++mt)
    #pragma unroll
    for (int r = 0; r < 4; ++r) {
      int row = wr * 32 + mt * 16 + lg * 4 + r;
      int r_e = rblk + row;
      float mu = musig[row * 2], rs = musig[row * 2 + 1];
      int tok = tokArr[row];
      float wgt = wArr[row];
      if (r_e < cnt && wgt != 0.f) {
        #pragma unroll
        for (int nt = 0; nt < 4; ++nt) {
          int col = wc * 64 + nt * 16 + lc;
          float v = ((acc[mt][nt][r] - mu) * rs * s2v[nt] + c2v[nt]) * wgt;
          unsafeAtomicAdd(out + (size_t)tok * 256 + col, v);
        }
      }
    }
}

// ---- C: combine: out = relu(x0 + g0*ybuf[2t] + g1*ybuf[2t+1]) ----
__global__ __launch_bounds__(256) void k_combine(
    const float* __restrict__ x0, const uint2* __restrict__ pairRW,
    const u16* __restrict__ ybuf, float* __restrict__ out) {
  int tid = threadIdx.x;
  int wv = tid >> 6, lane = tid & 63;
  int t = blockIdx.x * 4 + wv;
  uint2 r0 = pairRW[2 * t], r1 = pairRW[2 * t + 1];
  float4 acc = *reinterpret_cast<const float4*>(x0 + (size_t)t * 256 + lane * 4);
  if (r0.x != 0xFFFFFFFFu) {
    float g; __builtin_memcpy(&g, &r0.y, 4);
    uint2 yv = *reinterpret_cast<const uint2*>((const char*)ybuf + (size_t)(2 * t) * 512 + lane * 8);
    acc.x += g * bfbits(yv.x & 0xFFFFu);
    acc.y += g * bfbits(yv.x >> 16);
    acc.z += g * bfbits(yv.y & 0xFFFFu);
    acc.w += g * bfbits(yv.y >> 16);
  }
  if (r1.x != 0xFFFFFFFFu) {
    float g; __builtin_memcpy(&g, &r1.y, 4);
    uint2 yv = *reinterpret_cast<const uint2*>((const char*)ybuf + (size_t)(2 * t + 1) * 512 + lane * 8);
    acc.x += g * bfbits(yv.x & 0xFFFFu);
    acc.y += g * bfbits(yv.x >> 16);
    acc.z += g * bfbits(yv.y & 0xFFFFu);
    acc.w += g * bfbits(yv.y >> 16);
  }
  acc.x = fmaxf(acc.x, 0.f); acc.y = fmaxf(acc.y, 0.f);
  acc.z = fmaxf(acc.z, 0.f); acc.w = fmaxf(acc.w, 0.f);
  *reinterpret_cast<float4*>(out + (size_t)t * 256 + lane * 4) = acc;
}

// ---- F: out = relu(x0 + out) (atomic path) ----
__global__ __launch_bounds__(256) void k_final(
    const float* __restrict__ x0, float* __restrict__ out) {
  size_t i = ((size_t)blockIdx.x * 256 + threadIdx.x) * 8;
  float4 a0 = *reinterpret_cast<const float4*>(x0 + i);
  float4 a1 = *reinterpret_cast<const float4*>(x0 + i + 4);
  float4 b0 = *reinterpret_cast<float4*>(out + i);
  float4 b1 = *reinterpret_cast<float4*>(out + i + 4);
  b0.x = fmaxf(a0.x + b0.x, 0.f); b0.y = fmaxf(a0.y + b0.y, 0.f);
  b0.z = fmaxf(a0.z + b0.z, 0.f); b0.w = fmaxf(a0.w + b0.w, 0.f);
  b1.x = fmaxf(a1.x + b1.x, 0.f); b1.y = fmaxf(a1.y + b1.y, 0.f);
  b1.z = fmaxf(a1.z + b1.z, 0.f); b1.w = fmaxf(a1.w + b1.w, 0.f);
  *reinterpret_cast<float4*>(out + i) = b0;
  *reinterpret_cast<float4*>(out + i + 4) = b1;
}

// ================= FALLBACK (round-6, proven) =================

__global__ __launch_bounds__(256) void k_router_fb(
    const float* __restrict__ x0, const float* __restrict__ Wr, const float* __restrict__ br,
    float* __restrict__ outb) {
  __shared__ double sWr[256][8];
  __shared__ double sbr[8];
  int tid = threadIdx.x;
  #pragma unroll
  for (int e = 0; e < 8; ++e) sWr[tid][e] = (double)Wr[tid * 8 + e];
  if (tid < 8) sbr[tid] = (double)br[tid];
  __syncthreads();
  int t = blockIdx.x * 256 + tid;
  const float* xr = x0 + (size_t)t * 256;
  double acc[8];
  #pragma unroll
  for (int e = 0; e < 8; ++e) acc[e] = sbr[e];
  for (int dc = 0; dc < 256; dc += 4) {
    float4 xv = *reinterpret_cast<const float4*>(xr + dc);
    double xd[4] = {(double)xv.x, (double)xv.y, (double)xv.z, (double)xv.w};
    #pragma unroll
    for (int q = 0; q < 4; ++q)
      #pragma unroll
      for (int e = 0; e < 8; ++e) acc[e] += xd[q] * sWr[dc + q][e];
  }
  double v0 = -1e300, v1 = -1e300; int e0 = 0, e1 = 0;
  #pragma unroll
  for (int e = 0; e < 8; ++e) {
    double v = acc[e];
    if (v > v0) { v1 = v0; e1 = e0; v0 = v; e0 = e; }
    else if (v > v1) { v1 = v; e1 = e; }
  }
  double tt = exp(v1 - v0);
  double inv = 1.0 / (1.0 + tt);
  float g0 = (float)inv, g1 = (float)(tt * inv);
  uint4 rec;
  __builtin_memcpy(&rec.x, &g0, 4);
  __builtin_memcpy(&rec.y, &g1, 4);
  rec.z = (u32)e0 | ((u32)e1 << 8);
  rec.w = 0u;
  *reinterpret_cast<uint4*>((char*)outb + (size_t)t * 1024) = rec;
}

__global__ __launch_bounds__(1024) void k_scan_fb(float* __restrict__ outb) {
  __shared__ u32 wavetot[16][8];
  __shared__ u32 wavebase[16][8];
  int tid = threadIdx.x;
  int lane = tid & 63, w = tid >> 6;
  int t0 = tid * 64;
  u32 c[8] = {0, 0, 0, 0, 0, 0, 0, 0};
  for (int i = 0; i < 64; ++i) {
    uint4 rec = *reinterpret_cast<const uint4*>((const char*)outb + (size_t)(t0 + i) * 1024);
    int e0 = rec.z & 255, e1 = (rec.z >> 8) & 255;
    #pragma unroll
    for (int j = 0; j < 8; ++j) { c[j] += (e0 == j); c[j] += (e1 == j); }
  }
  u32 inc[8];
  #pragma unroll
  for (int j = 0; j < 8; ++j) inc[j] = c[j];
  for (int d = 1; d < 64; d <<= 1) {
    #pragma unroll
    for (int j = 0; j < 8; ++j) {
      u32 n = __shfl_up(inc[j], d);
      if (lane >= d) inc[j] += n;
    }
  }
  if (lane == 63) {
    #pragma unroll
    for (int j = 0; j < 8; ++j) wavetot[w][j] = inc[j];
  }
  __syncthreads();
  if (tid < 8) {
    u32 run = 0;
    for (int ww = 0; ww < 16; ++ww) { wavebase[ww][tid] = run; run += wavetot[ww][tid]; }
  }
  __syncthreads();
  u32 run[8];
  #pragma unroll
  for (int j = 0; j < 8; ++j) run[j] = wavebase[w][j] + inc[j] - c[j];
  for (int i = 0; i < 64; ++i) {
    char* rp = (char*)outb + (size_t)(t0 + i) * 1024;
    uint4 rec = *reinterpret_cast<const uint4*>(rp);
    int e0 = rec.z & 255, e1 = (rec.z >> 8) & 255;
    u32 pos0 = run[e0]; run[e0]++;
    u32 pos1 = run[e1]; run[e1]++;
    if (pos0 >= (u32)CAP) rec.x = 0u;
    if (pos1 >= (u32)CAP) rec.y = 0u;
    *reinterpret_cast<uint4*>(rp) = rec;
  }
}

__global__ __launch_bounds__(256) void k_mlp_fb(
    const float* __restrict__ x0,
    const float* __restrict__ W1, const float* __restrict__ b1,
    const float* __restrict__ ln1s, const float* __restrict__ ln1b,
    const float* __restrict__ W2, const float* __restrict__ b2,
    const float* __restrict__ ln2s, const float* __restrict__ ln2b,
    float* __restrict__ outb) {
  __shared__ float xs[256], hs[256];
  __shared__ float red[8];
  __shared__ uint4 recS;
  int tid = threadIdx.x;
  int w = tid >> 6, lane = tid & 63;
  int t = blockIdx.x;
  if (tid == 0) recS = *reinterpret_cast<const uint4*>((const char*)outb + (size_t)t * 1024);
  float x = x0[(size_t)t * 256 + tid];
  xs[tid] = x;
  __syncthreads();
  float gA, gB;
  __builtin_memcpy(&gA, &recS.x, 4);
  __builtin_memcpy(&gB, &recS.y, 4);
  int eA = recS.z & 255, eB = (recS.z >> 8) & 255;
  float mix = x;
  for (int s = 0; s < 2; ++s) {
    float gg = s ? gB : gA;
    int ee = s ? eB : eA;
    if (gg == 0.f) continue;
    const float* Wp = W1 + ((size_t)ee << 16) + tid;
    float h = b1[ee * 256 + tid];
    for (int d = 0; d < 256; d += 4) {
      h += xs[d + 0] * Wp[(size_t)(d + 0) * 256];
      h += xs[d + 1] * Wp[(size_t)(d + 1) * 256];
      h += xs[d + 2] * Wp[(size_t)(d + 2) * 256];
      h += xs[d + 3] * Wp[(size_t)(d + 3) * 256];
    }
    float sS = h, sQ = h * h;
    #pragma unroll
    for (int d = 1; d < 64; d <<= 1) { sS += __shfl_xor(sS, d); sQ += __shfl_xor(sQ, d); }
    if (lane == 0) { red[w] = sS; red[4 + w] = sQ; }
    __syncthreads();
    float S = red[0] + red[1] + red[2] + red[3];
    float Q = red[4] + red[5] + red[6] + red[7];
    float mu = S * (1.f / 256.f);
    float var = fmaxf(Q * (1.f / 256.f) - mu * mu, 0.f);
    float rs = rsqrtf(var + 1e-6f);
    float hn = fmaxf((h - mu) * rs * ln1s[ee * 256 + tid] + ln1b[ee * 256 + tid], 0.f);
    __syncthreads();
    hs[tid] = hn;
    __syncthreads();
    const float* W2p = W2 + ((size_t)ee << 16) + tid;
    float y = b2[ee * 256 + tid];
    for (int d = 0; d < 256; d += 4) {
      y += hs[d + 0] * W2p[(size_t)(d + 0) * 256];
      y += hs[d + 1] * W2p[(size_t)(d + 1) * 256];
      y += hs[d + 2] * W2p[(size_t)(d + 2) * 256];
      y += hs[d + 3] * W2p[(size_t)(d + 3) * 256];
    }
    float tS = y, tQ = y * y;
    #pragma unroll
    for (int d = 1; d < 64; d <<= 1) { tS += __shfl_xor(tS, d); tQ += __shfl_xor(tQ, d); }
    if (lane == 0) { red[w] = tS; red[4 + w] = tQ; }
    __syncthreads();
    float S2 = red[0] + red[1] + red[2] + red[3];
    float Q2 = red[4] + red[5] + red[6] + red[7];
    float mu2 = S2 * (1.f / 256.f);
    float var2 = fmaxf(Q2 * (1.f / 256.f) - mu2 * mu2, 0.f);
    float rs2 = rsqrtf(var2 + 1e-6f);
    float yn = (y - mu2) * rs2 * ln2s[ee * 256 + tid] + ln2b[ee * 256 + tid];
    mix += gg * yn;
    __syncthreads();
  }
  outb[(size_t)t * 256 + tid] = fmaxf(mix, 0.f);
}

extern "C" void kernel_launch(void* const* d_in, const int* in_sizes, int n_in,
                              void* d_out, int out_size, void* d_ws, size_t ws_size,
                              hipStream_t stream) {
  (void)in_sizes; (void)n_in; (void)out_size;
  const float* x0 = (const float*)d_in[0];
  const float* Wr = (const float*)d_in[1];
  const float* br = (const float*)d_in[2];
  const float* W1 = (const float*)d_in[3];
  const float* b1 = (const float*)d_in[4];
  const float* ln1s = (const float*)d_in[5];
  const float* ln1b = (const float*)d_in[6];
  const float* W2 = (const float*)d_in[7];
  const float* b2 = (const float*)d_in[8];
  const float* ln2s = (const float*)d_in[9];
  const float* ln2b = (const float*)d_in[10];
  float* outb = (float*)d_out;

  if (ws_size >= (size_t)WS_ATOM) {
    char* ws = (char*)d_ws;
    u16* W1F = (u16*)(ws + MW_W1F);
    u16* W2F = (u16*)(ws + MW_W2F);
    uint4* recAll = (uint4*)(ws + MW_REC);
    uint2* pairRW = (uint2*)(ws + MW_PRW);
    int* cntE = (int*)(ws + MW_CNT);
    u32* blkCnt = (u32*)(ws + MW_BCNT);
    u32* blkBase = (u32*)(ws + MW_BBASE);
    uint2* idx = (uint2*)(ws + MW_IDX);

    k_router_f<<<256, 256, 0, stream>>>(x0, Wr, br, recAll);
    k_count<<<256, 256, 0, stream>>>(recAll, blkCnt);
    k_offset<<<1, 256, 0, stream>>>(blkCnt, blkBase, cntE);
    k_place<<<256, 256, 0, stream>>>(recAll, blkBase, idx, pairRW);
    if (ws_size >= (size_t)WS_FAST) {
      u16* ybuf = (u16*)(ws + MW_YBUF);
      k_pack<<<dim3(128, 8, 2), 64, 0, stream>>>(W1, W2, W1F, W2F);
      k_expert_g<<<dim3(256, 8), 512, 0, stream>>>(x0, W1F, b1, ln1s, ln1b, W2F, b2, ln2s, ln2b,
                                                   idx, cntE, ybuf);
      k_combine<<<16384, 256, 0, stream>>>(x0, pairRW, ybuf, outb);
    } else {
      u16* W1T = (u16*)(ws + MW_W1T);
      u16* W2T = (u16*)(ws + MW_W2T);
      k_transpose<<<dim3(64, 8, 2), 256, 0, stream>>>(W1, W2, W1T, W2T);
      hipMemsetAsync(d_out, 0, (size_t)NTOK * 256 * 4, stream);
      k_expert<<<dim3(256, 8), 512, 0, stream>>>(x0, W1T, b1, ln1s, ln1b, W2T, b2, ln2s, ln2b,
                                                 idx, cntE, outb);
      k_final<<<8192, 256, 0, stream>>>(x0, outb);
    }
  } else {
    k_router_fb<<<256, 256, 0, stream>>>(x0, Wr, br, outb);
    k_scan_fb<<<1, 1024, 0, stream>>>(outb);
    k_mlp_fb<<<NTOK, 256, 0, stream>>>(x0, W1, b1, ln1s, ln1b, W2, b2, ln2s, ln2b, outb);
  }
}

// Round 18
// 157.372 us; speedup vs baseline: 1.1623x; 1.1623x over previous
//
#include <hip/hip_runtime.h>
#include <stdint.h>

#define NTOK 65536
#define CAP 16384

typedef unsigned int u32;
typedef unsigned short u16;
typedef short short8 __attribute__((ext_vector_type(8)));   // 8 bf16 bit-patterns (MFMA frag)
typedef float f32x4 __attribute__((ext_vector_type(4)));

// ---- ws layout ----
#define MW_W1F   0u           // 1MB fragment-major W1
#define MW_W2F   1048576u     // 1MB fragment-major W2
#define MW_REC   2097152u     // 65536 x uint4
#define MW_PRW   3145728u     // 131072 x uint2 {exRow|~0, gateBits}
#define MW_CNT   4194304u     // 8 x int
#define MW_BCNT  4202496u     // 256 x 8 u32
#define MW_BBASE 4210688u     // 256 x 8 u32
#define MW_IDX   5242880u     // 8 x CAP x uint2 {pair, gateBits}
#define MW_W1T   6291456u     // atomic tier
#define MW_W2T   7340032u
#define WS_ATOM  8388608u
#define MW_YBUF  8388608u     // 131072 x 512B bf16 rows, indexed by PAIR
#define WS_FAST  75497472u

__device__ __forceinline__ u16 f2bf(float f) {
  __bf16 h = (__bf16)f;                       // native RNE cast (v_cvt)
  u16 u; __builtin_memcpy(&u, &h, 2); return u;
}
__device__ __forceinline__ float bfbits(u32 b16) {
  u32 x = b16 << 16; float f; __builtin_memcpy(&f, &x, 4); return f;
}
__device__ __forceinline__ f32x4 zero4() {
  f32x4 z; z[0] = 0.f; z[1] = 0.f; z[2] = 0.f; z[3] = 0.f; return z;
}

// ---- P: pack W into fragment-major layout ----
__global__ __launch_bounds__(64) void k_pack(
    const float* __restrict__ W1, const float* __restrict__ W2,
    u16* __restrict__ W1F, u16* __restrict__ W2F) {
  int lane = threadIdx.x;
  int chunk = blockIdx.x;            // ks*16 + ntile
  int e = blockIdx.y;
  const float* S = (blockIdx.z ? W2 : W1) + ((size_t)e << 16);
  u16* D = (blockIdx.z ? W2F : W1F) + (((size_t)e * 128 + chunk) * 64 + lane) * 8;
  int ks = chunk >> 4, ntile = chunk & 15;
  int lg = lane >> 4, lc = lane & 15;
  int n = ntile * 16 + lc;
  int k0 = ks * 32 + lg * 8;
  u16 v[8];
  #pragma unroll
  for (int j = 0; j < 8; ++j) v[j] = f2bf(S[(size_t)(k0 + j) * 256 + n]);
  uint4 pk;
  pk.x = (u32)v[0] | ((u32)v[1] << 16);
  pk.y = (u32)v[2] | ((u32)v[3] << 16);
  pk.z = (u32)v[4] | ((u32)v[5] << 16);
  pk.w = (u32)v[6] | ((u32)v[7] << 16);
  *reinterpret_cast<uint4*>(D) = pk;
}

// ---- T: transpose (atomic tier only) ----
__global__ __launch_bounds__(256) void k_transpose(
    const float* __restrict__ W1, const float* __restrict__ W2,
    u16* __restrict__ W1T, u16* __restrict__ W2T) {
  __shared__ u16 t[32][33];
  int tile = blockIdx.x, e = blockIdx.y;
  const float* S = (blockIdx.z ? W2 : W1) + (size_t)e * 65536;
  u16* D = (blockIdx.z ? W2T : W1T) + (size_t)e * 65536;
  int r0 = (tile >> 3) * 32, c0 = (tile & 7) * 32;
  int tr = threadIdx.x >> 5, tc = threadIdx.x & 31;
  #pragma unroll
  for (int i = 0; i < 32; i += 8) t[tr + i][tc] = f2bf(S[(size_t)(r0 + tr + i) * 256 + c0 + tc]);
  __syncthreads();
  #pragma unroll
  for (int i = 0; i < 32; i += 8) D[(size_t)(c0 + tr + i) * 256 + r0 + tc] = t[tc][tr + i];
}

// ---- R: router (f64, top-2, softmax) ----
__global__ __launch_bounds__(256) void k_router_f(
    const float* __restrict__ x0, const float* __restrict__ Wr, const float* __restrict__ br,
    uint4* __restrict__ recAll) {
  __shared__ double sWr[256][8];
  __shared__ double sbr[8];
  int tid = threadIdx.x;
  #pragma unroll
  for (int e = 0; e < 8; ++e) sWr[tid][e] = (double)Wr[tid * 8 + e];
  if (tid < 8) sbr[tid] = (double)br[tid];
  __syncthreads();
  int t = blockIdx.x * 256 + tid;
  const float* xr = x0 + (size_t)t * 256;
  double acc[8];
  #pragma unroll
  for (int e = 0; e < 8; ++e) acc[e] = sbr[e];
  for (int dc = 0; dc < 256; dc += 4) {
    float4 xv = *reinterpret_cast<const float4*>(xr + dc);
    double xd[4] = {(double)xv.x, (double)xv.y, (double)xv.z, (double)xv.w};
    #pragma unroll
    for (int q = 0; q < 4; ++q)
      #pragma unroll
      for (int e = 0; e < 8; ++e) acc[e] += xd[q] * sWr[dc + q][e];
  }
  double v0 = -1e300, v1 = -1e300; int e0 = 0, e1 = 0;
  #pragma unroll
  for (int e = 0; e < 8; ++e) {
    double v = acc[e];
    if (v > v0) { v1 = v0; e1 = e0; v0 = v; e0 = e; }
    else if (v > v1) { v1 = v; e1 = e; }
  }
  double tt = exp(v1 - v0);
  double inv = 1.0 / (1.0 + tt);
  float g0 = (float)inv, g1 = (float)(tt * inv);
  uint4 rec;
  __builtin_memcpy(&rec.x, &g0, 4);
  __builtin_memcpy(&rec.y, &g1, 4);
  rec.z = (u32)e0 | ((u32)e1 << 8);
  rec.w = 0u;
  recAll[t] = rec;
}

// ---- S1: per-block expert histogram ----
__global__ __launch_bounds__(256) void k_count(
    const uint4* __restrict__ recAll, u32* __restrict__ blkCnt) {
  __shared__ u32 hist[8];
  int tid = threadIdx.x;
  if (tid < 8) hist[tid] = 0;
  __syncthreads();
  uint4 rec = recAll[blockIdx.x * 256 + tid];
  atomicAdd(&hist[rec.z & 255], 1u);
  atomicAdd(&hist[(rec.z >> 8) & 255], 1u);
  __syncthreads();
  if (tid < 8) blkCnt[blockIdx.x * 8 + tid] = hist[tid];
}

// ---- S2: exclusive scan of block-counts per expert ----
__global__ __launch_bounds__(256) void k_offset(
    const u32* __restrict__ blkCnt, u32* __restrict__ blkBase, int* __restrict__ cntE) {
  __shared__ u32 s[2048];
  int tid = threadIdx.x;
  #pragma unroll
  for (int i = 0; i < 8; ++i) s[tid + i * 256] = blkCnt[tid + i * 256];
  __syncthreads();
  if (tid < 8) {
    u32 run = 0;
    for (int b = 0; b < 256; ++b) {
      u32 v = s[b * 8 + tid];
      s[b * 8 + tid] = run;
      run += v;
    }
    cntE[tid] = (int)(run < (u32)CAP ? run : (u32)CAP);
  }
  __syncthreads();
  #pragma unroll
  for (int i = 0; i < 8; ++i) blkBase[tid + i * 256] = s[tid + i * 256];
}

// ---- S3: place pairs in exact global order -> idx lists + pairRW ----
__global__ __launch_bounds__(256) void k_place(
    const uint4* __restrict__ recAll, const u32* __restrict__ blkBase,
    uint2* __restrict__ idx, uint2* __restrict__ pairRW) {
  __shared__ u32 wavetot[4][8];
  __shared__ u32 wavebase[4][8];
  int tid = threadIdx.x;
  int lane = tid & 63, w = tid >> 6;
  int t = blockIdx.x * 256 + tid;
  uint4 rec = recAll[t];
  int e0 = rec.z & 255, e1 = (rec.z >> 8) & 255;
  u32 c[8];
  #pragma unroll
  for (int j = 0; j < 8; ++j) c[j] = (u32)(e0 == j) + (u32)(e1 == j);
  u32 inc[8];
  #pragma unroll
  for (int j = 0; j < 8; ++j) inc[j] = c[j];
  for (int d = 1; d < 64; d <<= 1) {
    #pragma unroll
    for (int j = 0; j < 8; ++j) {
      u32 n = __shfl_up(inc[j], d);
      if (lane >= d) inc[j] += n;
    }
  }
  if (lane == 63) {
    #pragma unroll
    for (int j = 0; j < 8; ++j) wavetot[w][j] = inc[j];
  }
  __syncthreads();
  if (tid < 8) {
    u32 run = 0;
    for (int ww = 0; ww < 4; ++ww) { wavebase[ww][tid] = run; run += wavetot[ww][tid]; }
  }
  __syncthreads();
  u32 run[8];
  #pragma unroll
  for (int j = 0; j < 8; ++j)
    run[j] = blkBase[blockIdx.x * 8 + j] + wavebase[w][j] + inc[j] - c[j];
  u32 p0 = run[e0]++;
  u32 p1 = run[e1]++;
  uint2 rw0, rw1;
  if (p0 < (u32)CAP) { idx[(u32)e0 * CAP + p0] = make_uint2((u32)(2 * t), rec.x); rw0 = make_uint2((u32)e0 * CAP + p0, rec.x); }
  else rw0 = make_uint2(0xFFFFFFFFu, 0u);
  if (p1 < (u32)CAP) { idx[(u32)e1 * CAP + p1] = make_uint2((u32)(2 * t + 1), rec.y); rw1 = make_uint2((u32)e1 * CAP + p1, rec.y); }
  else rw1 = make_uint2(0xFFFFFFFFu, 0u);
  pairRW[2 * t] = rw0;
  pairRW[2 * t + 1] = rw1;
}

// ---- E_g: gather-A expert MLP, frag-major B, ybuf indexed by pair (r15-proven epilogue) ----
__global__ __launch_bounds__(512, 4) void k_expert_g(
    const float* __restrict__ x0,
    const u16* __restrict__ W1F, const float* __restrict__ b1,
    const float* __restrict__ ln1s, const float* __restrict__ ln1b,
    const u16* __restrict__ W2F, const float* __restrict__ b2,
    const float* __restrict__ ln2s, const float* __restrict__ ln2b,
    const uint2* __restrict__ idx2, const int* __restrict__ cntE,
    u16* __restrict__ ybuf) {
  __shared__ __attribute__((aligned(16))) char sm[32768];
  __shared__ float red[512];     // [64][4][2]
  __shared__ float musig[128];   // [64][2]
  __shared__ int pArr[64];

  const int e = blockIdx.y;
  const int cnt = cntE[e];
  const int rblk = blockIdx.x * 64;
  if (rblk >= cnt) return;

  const int tid = threadIdx.x;
  const int w = tid >> 6, lane = tid & 63;
  const int wr = w >> 2, wc = w & 3;
  const int lg = lane >> 4, lc = lane & 15;
  const int ncol = wc * 64 + lc;

  // gather 64 rows (f32 -> bf16), XOR-swizzled 16B slots (slot ^= row&7)
  #pragma unroll
  for (int it = 0; it < 4; ++it) {
    int id = tid + it * 512;
    int row = id >> 5, s = id & 31;
    int r = rblk + row;
    uint2 en = make_uint2(0u, 0u);
    if (r < cnt) en = idx2[e * CAP + r];
    if (s == 0) pArr[row] = (int)en.x;
    int tok = (int)(en.x >> 1);
    int ssrc = s ^ (row & 7);
    const float* src = x0 + (size_t)tok * 256 + ssrc * 8;
    float4 f0 = *reinterpret_cast<const float4*>(src);
    float4 f1 = *reinterpret_cast<const float4*>(src + 4);
    uint4 pk;
    pk.x = (u32)f2bf(f0.x) | ((u32)f2bf(f0.y) << 16);
    pk.y = (u32)f2bf(f0.z) | ((u32)f2bf(f0.w) << 16);
    pk.z = (u32)f2bf(f1.x) | ((u32)f2bf(f1.y) << 16);
    pk.w = (u32)f2bf(f1.z) | ((u32)f2bf(f1.w) << 16);
    *reinterpret_cast<uint4*>(sm + row * 512 + s * 16) = pk;
  }
  __syncthreads();

  f32x4 acc[2][4];
  const u16* BF1 = W1F + (size_t)e * 128 * 64 * 8;
  const u16* BF2 = W2F + (size_t)e * 128 * 64 * 8;

#define GEMM(BF) do { \
    _Pragma("unroll") \
    for (int ks = 0; ks < 8; ++ks) { \
      short8 bfr[4]; \
      _Pragma("unroll") \
      for (int nt = 0; nt < 4; ++nt) \
        bfr[nt] = *reinterpret_cast<const short8*>((BF) + (((ks * 16) + wc * 4 + nt) * 64 + lane) * 8); \
      short8 afr[2]; \
      _Pragma("unroll") \
      for (int mt = 0; mt < 2; ++mt) { \
        int row = wr * 32 + mt * 16 + lc; \
        int slot = (ks * 4 + lg) ^ (row & 7); \
        afr[mt] = *reinterpret_cast<const short8*>(sm + row * 512 + slot * 16); \
      } \
      _Pragma("unroll") \
      for (int mt = 0; mt < 2; ++mt) \
        _Pragma("unroll") \
        for (int nt = 0; nt < 4; ++nt) \
          acc[mt][nt] = __builtin_amdgcn_mfma_f32_16x16x32_bf16(afr[mt], bfr[nt], acc[mt][nt], 0, 0, 0); \
    } \
  } while (0)

  // ---- GEMM1 ----
  #pragma unroll
  for (int mt = 0; mt < 2; ++mt)
    #pragma unroll
    for (int nt = 0; nt < 4; ++nt) acc[mt][nt] = zero4();
  GEMM(BF1);

  // ---- +b1, LN1 stats ----
  float s1v[4], c1v[4];
  {
    #pragma unroll
    for (int nt = 0; nt < 4; ++nt) {
      int n = ncol + nt * 16;
      float b1v = b1[e * 256 + n];
      s1v[nt] = ln1s[e * 256 + n];
      c1v[nt] = ln1b[e * 256 + n];
      #pragma unroll
      for (int mt = 0; mt < 2; ++mt)
        #pragma unroll
        for (int r = 0; r < 4; ++r) acc[mt][nt][r] += b1v;
    }
    #pragma unroll
    for (int mt = 0; mt < 2; ++mt)
      #pragma unroll
      for (int r = 0; r < 4; ++r) {
        float s = 0.f, q = 0.f;
        #pragma unroll
        for (int nt = 0; nt < 4; ++nt) { float v = acc[mt][nt][r]; s += v; q += v * v; }
        #pragma unroll
        for (int d = 1; d < 16; d <<= 1) { s += __shfl_xor(s, d); q += __shfl_xor(q, d); }
        if (lc == 0) {
          int row = wr * 32 + mt * 16 + lg * 4 + r;
          red[(row * 4 + wc) * 2 + 0] = s;
          red[(row * 4 + wc) * 2 + 1] = q;
        }
      }
  }
  __syncthreads();
  if (tid < 64) {
    float S = 0.f, Q = 0.f;
    #pragma unroll
    for (int j = 0; j < 4; ++j) { S += red[(tid * 4 + j) * 2]; Q += red[(tid * 4 + j) * 2 + 1]; }
    float mu = S * (1.f / 256.f);
    float var = fmaxf(Q * (1.f / 256.f) - mu * mu, 0.f);
    musig[tid * 2] = mu;
    musig[tid * 2 + 1] = rsqrtf(var + 1e-6f);
  }
  __syncthreads();

  // ---- LN1 + relu -> H (bf16) back into sm ----
  #pragma unroll
  for (int mt = 0; mt < 2; ++mt)
    #pragma unroll
    for (int r = 0; r < 4; ++r) {
      int row = wr * 32 + mt * 16 + lg * 4 + r;
      float mu = musig[row * 2], rs = musig[row * 2 + 1];
      #pragma unroll
      for (int nt = 0; nt < 4; ++nt) {
        float v = fmaxf((acc[mt][nt][r] - mu) * rs * s1v[nt] + c1v[nt], 0.f);
        int col = ncol + nt * 16;
        int slot = (col >> 3) ^ (row & 7);
        *reinterpret_cast<u16*>(sm + row * 512 + slot * 16 + (col & 7) * 2) = f2bf(v);
      }
    }
  __syncthreads();

  // ---- GEMM2 ----
  #pragma unroll
  for (int mt = 0; mt < 2; ++mt)
    #pragma unroll
    for (int nt = 0; nt < 4; ++nt) acc[mt][nt] = zero4();
  GEMM(BF2);
#undef GEMM

  // ---- +b2, LN2 stats ----
  float s2v[4], c2v[4];
  #pragma unroll
  for (int nt = 0; nt < 4; ++nt) {
    int n = ncol + nt * 16;
    float b2v = b2[e * 256 + n];
    s2v[nt] = ln2s[e * 256 + n];
    c2v[nt] = ln2b[e * 256 + n];
    #pragma unroll
    for (int mt = 0; mt < 2; ++mt)
      #pragma unroll
      for (int r = 0; r < 4; ++r) acc[mt][nt][r] += b2v;
  }
  __syncthreads();
  #pragma unroll
  for (int mt = 0; mt < 2; ++mt)
    #pragma unroll
    for (int r = 0; r < 4; ++r) {
      float s = 0.f, q = 0.f;
      #pragma unroll
      for (int nt = 0; nt < 4; ++nt) { float v = acc[mt][nt][r]; s += v; q += v * v; }
      #pragma unroll
      for (int d = 1; d < 16; d <<= 1) { s += __shfl_xor(s, d); q += __shfl_xor(q, d); }
      if (lc == 0) {
        int row = wr * 32 + mt * 16 + lg * 4 + r;
        red[(row * 4 + wc) * 2 + 0] = s;
        red[(row * 4 + wc) * 2 + 1] = q;
      }
    }
  __syncthreads();
  if (tid < 64) {
    float S = 0.f, Q = 0.f;
    #pragma unroll
    for (int j = 0; j < 4; ++j) { S += red[(tid * 4 + j) * 2]; Q += red[(tid * 4 + j) * 2 + 1]; }
    float mu = S * (1.f / 256.f);
    float var = fmaxf(Q * (1.f / 256.f) - mu * mu, 0.f);
    musig[tid * 2] = mu;
    musig[tid * 2 + 1] = rsqrtf(var + 1e-6f);
  }
  __syncthreads();

  // ---- LN2 + ybuf[pair] write (packed u32 stores; r15-proven) ----
  #pragma unroll
  for (int mt = 0; mt < 2; ++mt)
    #pragma unroll
    for (int r = 0; r < 4; ++r) {
      int row = wr * 32 + mt * 16 + lg * 4 + r;
      int r_e = rblk + row;
      float mu = musig[row * 2], rs = musig[row * 2 + 1];
      int pair = pArr[row];
      #pragma unroll
      for (int nt = 0; nt < 4; ++nt) {
        float v = (acc[mt][nt][r] - mu) * rs * s2v[nt] + c2v[nt];
        u32 yb = (u32)f2bf(v);
        u32 ob = (u32)__shfl_xor((int)yb, 1);
        if (((lane & 1) == 0) && (r_e < cnt)) {
          u32 pk = yb | (ob << 16);
          int col = ncol + nt * 16;
          *reinterpret_cast<u32*>((char*)ybuf + (size_t)pair * 512 + col * 2) = pk;
        }
      }
    }
}

// ---- E (atomic tier): gather version, gated f32 atomics ----
__global__ __launch_bounds__(512, 4) void k_expert(
    const float* __restrict__ x0,
    const u16* __restrict__ W1T, const float* __restrict__ b1,
    const float* __restrict__ ln1s, const float* __restrict__ ln1b,
    const u16* __restrict__ W2T, const float* __restrict__ b2,
    const float* __restrict__ ln2s, const float* __restrict__ ln2b,
    const uint2* __restrict__ idx2, const int* __restrict__ cntE,
    float* __restrict__ out) {
  __shared__ __attribute__((aligned(16))) char sm[32768];
  __shared__ float red[512];
  __shared__ float musig[128];
  __shared__ int tokArr[64];
  __shared__ float wArr[64];

  const int e = blockIdx.y;
  const int cnt = cntE[e];
  const int rblk = blockIdx.x * 64;
  if (rblk >= cnt) return;

  const int tid = threadIdx.x;
  const int w = tid >> 6, lane = tid & 63;
  const int wr = w >> 2, wc = w & 3;
  const int lg = lane >> 4, lc = lane & 15;

  #pragma unroll
  for (int it = 0; it < 4; ++it) {
    int id = tid + it * 512;
    int row = id >> 5, s = id & 31;
    int r = rblk + row;
    uint2 en = make_uint2(0u, 0u);
    if (r < cnt) en = idx2[e * CAP + r];
    if (s == 0) {
      tokArr[row] = (int)(en.x >> 1);
      float wv; __builtin_memcpy(&wv, &en.y, 4);
      wArr[row] = (r < cnt) ? wv : 0.f;
    }
    int tok = (int)(en.x >> 1);
    int ssrc = s ^ (row & 7);
    const float* src = x0 + (size_t)tok * 256 + ssrc * 8;
    float4 f0 = *reinterpret_cast<const float4*>(src);
    float4 f1 = *reinterpret_cast<const float4*>(src + 4);
    uint4 pk;
    pk.x = (u32)f2bf(f0.x) | ((u32)f2bf(f0.y) << 16);
    pk.y = (u32)f2bf(f0.z) | ((u32)f2bf(f0.w) << 16);
    pk.z = (u32)f2bf(f1.x) | ((u32)f2bf(f1.y) << 16);
    pk.w = (u32)f2bf(f1.z) | ((u32)f2bf(f1.w) << 16);
    *reinterpret_cast<uint4*>(sm + row * 512 + s * 16) = pk;
  }
  __syncthreads();

  f32x4 acc[2][4];
  #pragma unroll
  for (int mt = 0; mt < 2; ++mt)
    #pragma unroll
    for (int nt = 0; nt < 4; ++nt) acc[mt][nt] = zero4();

  {
    const u16* B1 = W1T + ((size_t)e << 16);
    #pragma unroll
    for (int ks = 0; ks < 8; ++ks) {
      short8 bfr[4];
      #pragma unroll
      for (int nt = 0; nt < 4; ++nt) {
        int n = wc * 64 + nt * 16 + lc;
        bfr[nt] = *reinterpret_cast<const short8*>(B1 + n * 256 + ks * 32 + lg * 8);
      }
      short8 afr[2];
      #pragma unroll
      for (int mt = 0; mt < 2; ++mt) {
        int row = wr * 32 + mt * 16 + lc;
        int slot = (ks * 4 + lg) ^ (row & 7);
        afr[mt] = *reinterpret_cast<const short8*>(sm + row * 512 + slot * 16);
      }
      #pragma unroll
      for (int mt = 0; mt < 2; ++mt)
        #pragma unroll
        for (int nt = 0; nt < 4; ++nt)
          acc[mt][nt] = __builtin_amdgcn_mfma_f32_16x16x32_bf16(afr[mt], bfr[nt], acc[mt][nt], 0, 0, 0);
    }
  }

  float s1v[4], c1v[4];
  {
    #pragma unroll
    for (int nt = 0; nt < 4; ++nt) {
      int n = wc * 64 + nt * 16 + lc;
      float b1v = b1[e * 256 + n];
      s1v[nt] = ln1s[e * 256 + n];
      c1v[nt] = ln1b[e * 256 + n];
      #pragma unroll
      for (int mt = 0; mt < 2; ++mt)
        #pragma unroll
        for (int r = 0; r < 4; ++r) acc[mt][nt][r] += b1v;
    }
    #pragma unroll
    for (int mt = 0; mt < 2; ++mt)
      #pragma unroll
      for (int r = 0; r < 4; ++r) {
        float s = 0.f, q = 0.f;
        #pragma unroll
        for (int nt = 0; nt < 4; ++nt) { float v = acc[mt][nt][r]; s += v; q += v * v; }
        #pragma unroll
        for (int d = 1; d < 16; d <<= 1) { s += __shfl_xor(s, d); q += __shfl_xor(q, d); }
        if (lc == 0) {
          int row = wr * 32 + mt * 16 + lg * 4 + r;
          red[(row * 4 + wc) * 2 + 0] = s;
          red[(row * 4 + wc) * 2 + 1] = q;
        }
      }
  }
  __syncthreads();
  if (tid < 64) {
    float S = 0.f, Q = 0.f;
    #pragma unroll
    for (int j = 0; j < 4; ++j) { S += red[(tid * 4 + j) * 2]; Q += red[(tid * 4 + j) * 2 + 1]; }
    float mu = S * (1.f / 256.f);
    float var = fmaxf(Q * (1.f / 256.f) - mu * mu, 0.f);
    musig[tid * 2] = mu;
    musig[tid * 2 + 1] = rsqrtf(var + 1e-6f);
  }
  __syncthreads();

  #pragma unroll
  for (int mt = 0; mt < 2; ++mt)
    #pragma unroll
    for (int r = 0; r < 4; ++r) {
      int row = wr * 32 + mt * 16 + lg * 4 + r;
      float mu = musig[row * 2], rs = musig[row * 2 + 1];
      #pragma unroll
      for (int nt = 0; nt < 4; ++nt) {
        float v = fmaxf((acc[mt][nt][r] - mu) * rs * s1v[nt] + c1v[nt], 0.f);
        int col = wc * 64 + nt * 16 + lc;
        int slot = (col >> 3) ^ (row & 7);
        *reinterpret_cast<u16*>(sm + row * 512 + slot * 16 + (col & 7) * 2) = f2bf(v);
      }
    }
  __syncthreads();

  #pragma unroll
  for (int mt = 0; mt < 2; ++mt)
    #pragma unroll
    for (int nt = 0; nt < 4; ++nt) acc[mt][nt] = zero4();
  {
    const u16* B2 = W2T + ((size_t)e << 16);
    #pragma unroll
    for (int ks = 0; ks < 8; ++ks) {
      short8 bfr[4];
      #pragma unroll
      for (int nt = 0; nt < 4; ++nt) {
        int n = wc * 64 + nt * 16 + lc;
        bfr[nt] = *reinterpret_cast<const short8*>(B2 + n * 256 + ks * 32 + lg * 8);
      }
      short8 afr[2];
      #pragma unroll
      for (int mt = 0; mt < 2; ++mt) {
        int row = wr * 32 + mt * 16 + lc;
        int slot = (ks * 4 + lg) ^ (row & 7);
        afr[mt] = *reinterpret_cast<const short8*>(sm + row * 512 + slot * 16);
      }
      #pragma unroll
      for (int mt = 0; mt < 2; ++mt)
        #pragma unroll
        for (int nt = 0; nt < 4; ++nt)
          acc[mt][nt] = __builtin_amdgcn_mfma_f32_16x16x32_bf16(afr[mt], bfr[nt], acc[mt][nt], 0, 0, 0);
    }
  }

  float s2v[4], c2v[4];
  #pragma unroll
  for (int nt = 0; nt < 4; ++nt) {
    int n = wc * 64 + nt * 16 + lc;
    float b2v = b2[e * 256 + n];
    s2v[nt] = ln2s[e * 256 + n];
    c2v[nt] = ln2b[e * 256 + n];
    #pragma unroll
    for (int mt = 0; mt < 2; ++mt)
      #pragma unroll
      for (int r = 0; r < 4; ++r) acc[mt][nt][r] += b2v;
  }
  __syncthreads();
  #pragma unroll
  for (int mt = 0; mt < 2; ++mt)
    #pragma unroll
    for (int r = 0; r < 4; ++r) {
      float s = 0.f, q = 0.f;
      #pragma unroll
      for (int nt = 0; nt < 4; ++nt) { float v = acc[mt][nt][r]; s += v; q += v * v; }
      #pragma unroll
      for (int d = 1; d < 16; d <<= 1) { s += __shfl_xor(s, d); q += __shfl_xor(q, d); }
      if (lc == 0) {
        int row = wr * 32 + mt * 16 + lg * 4 + r;
        red[(row * 4 + wc) * 2 + 0] = s;
        red[(row * 4 + wc) * 2 + 1] = q;
      }
    }
  __syncthreads();
  if (tid < 64) {
    float S = 0.f, Q = 0.f;
    #pragma unroll
    for (int j = 0; j < 4; ++j) { S += red[(tid * 4 + j) * 2]; Q += red[(tid * 4 + j) * 2 + 1]; }
    float mu = S * (1.f / 256.f);
    float var = fmaxf(Q * (1.f / 256.f) - mu * mu, 0.f);
    musig[tid * 2] = mu;
    musig[tid * 2 + 1] = rsqrtf(var + 1e-6f);
  }
  __syncthreads();

  #pragma unroll
  for (int mt = 0; mt < 2; ++mt)
    #pragma unroll
    for (int r = 0; r < 4; ++r) {
      int row = wr * 32 + mt * 16 + lg * 4 + r;
      int r_e = rblk + row;
      float mu = musig[row * 2], rs = musig[row * 2 + 1];
      int tok = tokArr[row];
      float wgt = wArr[row];
      if (r_e < cnt && wgt != 0.f) {
        #pragma unroll
        for (int nt = 0; nt < 4; ++nt) {
          int col = wc * 64 + nt * 16 + lc;
          float v = ((acc[mt][nt][r] - mu) * rs * s2v[nt] + c2v[nt]) * wgt;
          unsafeAtomicAdd(out + (size_t)tok * 256 + col, v);
        }
      }
    }
}

// ---- C: combine: out = relu(x0 + g0*ybuf[2t] + g1*ybuf[2t+1]) ----
__global__ __launch_bounds__(256) void k_combine(
    const float* __restrict__ x0, const uint2* __restrict__ pairRW,
    const u16* __restrict__ ybuf, float* __restrict__ out) {
  int tid = threadIdx.x;
  int wv = tid >> 6, lane = tid & 63;
  int t = blockIdx.x * 4 + wv;
  uint2 r0 = pairRW[2 * t], r1 = pairRW[2 * t + 1];
  float4 acc = *reinterpret_cast<const float4*>(x0 + (size_t)t * 256 + lane * 4);
  if (r0.x != 0xFFFFFFFFu) {
    float g; __builtin_memcpy(&g, &r0.y, 4);
    uint2 yv = *reinterpret_cast<const uint2*>((const char*)ybuf + (size_t)(2 * t) * 512 + lane * 8);
    acc.x += g * bfbits(yv.x & 0xFFFFu);
    acc.y += g * bfbits(yv.x >> 16);
    acc.z += g * bfbits(yv.y & 0xFFFFu);
    acc.w += g * bfbits(yv.y >> 16);
  }
  if (r1.x != 0xFFFFFFFFu) {
    float g; __builtin_memcpy(&g, &r1.y, 4);
    uint2 yv = *reinterpret_cast<const uint2*>((const char*)ybuf + (size_t)(2 * t + 1) * 512 + lane * 8);
    acc.x += g * bfbits(yv.x & 0xFFFFu);
    acc.y += g * bfbits(yv.x >> 16);
    acc.z += g * bfbits(yv.y & 0xFFFFu);
    acc.w += g * bfbits(yv.y >> 16);
  }
  acc.x = fmaxf(acc.x, 0.f); acc.y = fmaxf(acc.y, 0.f);
  acc.z = fmaxf(acc.z, 0.f); acc.w = fmaxf(acc.w, 0.f);
  *reinterpret_cast<float4*>(out + (size_t)t * 256 + lane * 4) = acc;
}

// ---- F: out = relu(x0 + out) (atomic path) ----
__global__ __launch_bounds__(256) void k_final(
    const float* __restrict__ x0, float* __restrict__ out) {
  size_t i = ((size_t)blockIdx.x * 256 + threadIdx.x) * 8;
  float4 a0 = *reinterpret_cast<const float4*>(x0 + i);
  float4 a1 = *reinterpret_cast<const float4*>(x0 + i + 4);
  float4 b0 = *reinterpret_cast<float4*>(out + i);
  float4 b1 = *reinterpret_cast<float4*>(out + i + 4);
  b0.x = fmaxf(a0.x + b0.x, 0.f); b0.y = fmaxf(a0.y + b0.y, 0.f);
  b0.z = fmaxf(a0.z + b0.z, 0.f); b0.w = fmaxf(a0.w + b0.w, 0.f);
  b1.x = fmaxf(a1.x + b1.x, 0.f); b1.y = fmaxf(a1.y + b1.y, 0.f);
  b1.z = fmaxf(a1.z + b1.z, 0.f); b1.w = fmaxf(a1.w + b1.w, 0.f);
  *reinterpret_cast<float4*>(out + i) = b0;
  *reinterpret_cast<float4*>(out + i + 4) = b1;
}

// ================= FALLBACK (round-6, proven) =================

__global__ __launch_bounds__(256) void k_router_fb(
    const float* __restrict__ x0, const float* __restrict__ Wr, const float* __restrict__ br,
    float* __restrict__ outb) {
  __shared__ double sWr[256][8];
  __shared__ double sbr[8];
  int tid = threadIdx.x;
  #pragma unroll
  for (int e = 0; e < 8; ++e) sWr[tid][e] = (double)Wr[tid * 8 + e];
  if (tid < 8) sbr[tid] = (double)br[tid];
  __syncthreads();
  int t = blockIdx.x * 256 + tid;
  const float* xr = x0 + (size_t)t * 256;
  double acc[8];
  #pragma unroll
  for (int e = 0; e < 8; ++e) acc[e] = sbr[e];
  for (int dc = 0; dc < 256; dc += 4) {
    float4 xv = *reinterpret_cast<const float4*>(xr + dc);
    double xd[4] = {(double)xv.x, (double)xv.y, (double)xv.z, (double)xv.w};
    #pragma unroll
    for (int q = 0; q < 4; ++q)
      #pragma unroll
      for (int e = 0; e < 8; ++e) acc[e] += xd[q] * sWr[dc + q][e];
  }
  double v0 = -1e300, v1 = -1e300; int e0 = 0, e1 = 0;
  #pragma unroll
  for (int e = 0; e < 8; ++e) {
    double v = acc[e];
    if (v > v0) { v1 = v0; e1 = e0; v0 = v; e0 = e; }
    else if (v > v1) { v1 = v; e1 = e; }
  }
  double tt = exp(v1 - v0);
  double inv = 1.0 / (1.0 + tt);
  float g0 = (float)inv, g1 = (float)(tt * inv);
  uint4 rec;
  __builtin_memcpy(&rec.x, &g0, 4);
  __builtin_memcpy(&rec.y, &g1, 4);
  rec.z = (u32)e0 | ((u32)e1 << 8);
  rec.w = 0u;
  *reinterpret_cast<uint4*>((char*)outb + (size_t)t * 1024) = rec;
}

__global__ __launch_bounds__(1024) void k_scan_fb(float* __restrict__ outb) {
  __shared__ u32 wavetot[16][8];
  __shared__ u32 wavebase[16][8];
  int tid = threadIdx.x;
  int lane = tid & 63, w = tid >> 6;
  int t0 = tid * 64;
  u32 c[8] = {0, 0, 0, 0, 0, 0, 0, 0};
  for (int i = 0; i < 64; ++i) {
    uint4 rec = *reinterpret_cast<const uint4*>((const char*)outb + (size_t)(t0 + i) * 1024);
    int e0 = rec.z & 255, e1 = (rec.z >> 8) & 255;
    #pragma unroll
    for (int j = 0; j < 8; ++j) { c[j] += (e0 == j); c[j] += (e1 == j); }
  }
  u32 inc[8];
  #pragma unroll
  for (int j = 0; j < 8; ++j) inc[j] = c[j];
  for (int d = 1; d < 64; d <<= 1) {
    #pragma unroll
    for (int j = 0; j < 8; ++j) {
      u32 n = __shfl_up(inc[j], d);
      if (lane >= d) inc[j] += n;
    }
  }
  if (lane == 63) {
    #pragma unroll
    for (int j = 0; j < 8; ++j) wavetot[w][j] = inc[j];
  }
  __syncthreads();
  if (tid < 8) {
    u32 run = 0;
    for (int ww = 0; ww < 16; ++ww) { wavebase[ww][tid] = run; run += wavetot[ww][tid]; }
  }
  __syncthreads();
  u32 run[8];
  #pragma unroll
  for (int j = 0; j < 8; ++j) run[j] = wavebase[w][j] + inc[j] - c[j];
  for (int i = 0; i < 64; ++i) {
    char* rp = (char*)outb + (size_t)(t0 + i) * 1024;
    uint4 rec = *reinterpret_cast<const uint4*>(rp);
    int e0 = rec.z & 255, e1 = (rec.z >> 8) & 255;
    u32 pos0 = run[e0]; run[e0]++;
    u32 pos1 = run[e1]; run[e1]++;
    if (pos0 >= (u32)CAP) rec.x = 0u;
    if (pos1 >= (u32)CAP) rec.y = 0u;
    *reinterpret_cast<uint4*>(rp) = rec;
  }
}

__global__ __launch_bounds__(256) void k_mlp_fb(
    const float* __restrict__ x0,
    const float* __restrict__ W1, const float* __restrict__ b1,
    const float* __restrict__ ln1s, const float* __restrict__ ln1b,
    const float* __restrict__ W2, const float* __restrict__ b2,
    const float* __restrict__ ln2s, const float* __restrict__ ln2b,
    float* __restrict__ outb) {
  __shared__ float xs[256], hs[256];
  __shared__ float red[8];
  __shared__ uint4 recS;
  int tid = threadIdx.x;
  int w = tid >> 6, lane = tid & 63;
  int t = blockIdx.x;
  if (tid == 0) recS = *reinterpret_cast<const uint4*>((const char*)outb + (size_t)t * 1024);
  float x = x0[(size_t)t * 256 + tid];
  xs[tid] = x;
  __syncthreads();
  float gA, gB;
  __builtin_memcpy(&gA, &recS.x, 4);
  __builtin_memcpy(&gB, &recS.y, 4);
  int eA = recS.z & 255, eB = (recS.z >> 8) & 255;
  float mix = x;
  for (int s = 0; s < 2; ++s) {
    float gg = s ? gB : gA;
    int ee = s ? eB : eA;
    if (gg == 0.f) continue;
    const float* Wp = W1 + ((size_t)ee << 16) + tid;
    float h = b1[ee * 256 + tid];
    for (int d = 0; d < 256; d += 4) {
      h += xs[d + 0] * Wp[(size_t)(d + 0) * 256];
      h += xs[d + 1] * Wp[(size_t)(d + 1) * 256];
      h += xs[d + 2] * Wp[(size_t)(d + 2) * 256];
      h += xs[d + 3] * Wp[(size_t)(d + 3) * 256];
    }
    float sS = h, sQ = h * h;
    #pragma unroll
    for (int d = 1; d < 64; d <<= 1) { sS += __shfl_xor(sS, d); sQ += __shfl_xor(sQ, d); }
    if (lane == 0) { red[w] = sS; red[4 + w] = sQ; }
    __syncthreads();
    float S = red[0] + red[1] + red[2] + red[3];
    float Q = red[4] + red[5] + red[6] + red[7];
    float mu = S * (1.f / 256.f);
    float var = fmaxf(Q * (1.f / 256.f) - mu * mu, 0.f);
    float rs = rsqrtf(var + 1e-6f);
    float hn = fmaxf((h - mu) * rs * ln1s[ee * 256 + tid] + ln1b[ee * 256 + tid], 0.f);
    __syncthreads();
    hs[tid] = hn;
    __syncthreads();
    const float* W2p = W2 + ((size_t)ee << 16) + tid;
    float y = b2[ee * 256 + tid];
    for (int d = 0; d < 256; d += 4) {
      y += hs[d + 0] * W2p[(size_t)(d + 0) * 256];
      y += hs[d + 1] * W2p[(size_t)(d + 1) * 256];
      y += hs[d + 2] * W2p[(size_t)(d + 2) * 256];
      y += hs[d + 3] * W2p[(size_t)(d + 3) * 256];
    }
    float tS = y, tQ = y * y;
    #pragma unroll
    for (int d = 1; d < 64; d <<= 1) { tS += __shfl_xor(tS, d); tQ += __shfl_xor(tQ, d); }
    if (lane == 0) { red[w] = tS; red[4 + w] = tQ; }
    __syncthreads();
    float S2 = red[0] + red[1] + red[2] + red[3];
    float Q2 = red[4] + red[5] + red[6] + red[7];
    float mu2 = S2 * (1.f / 256.f);
    float var2 = fmaxf(Q2 * (1.f / 256.f) - mu2 * mu2, 0.f);
    float rs2 = rsqrtf(var2 + 1e-6f);
    float yn = (y - mu2) * rs2 * ln2s[ee * 256 + tid] + ln2b[ee * 256 + tid];
    mix += gg * yn;
    __syncthreads();
  }
  outb[(size_t)t * 256 + tid] = fmaxf(mix, 0.f);
}

extern "C" void kernel_launch(void* const* d_in, const int* in_sizes, int n_in,
                              void* d_out, int out_size, void* d_ws, size_t ws_size,
                              hipStream_t stream) {
  (void)in_sizes; (void)n_in; (void)out_size;
  const float* x0 = (const float*)d_in[0];
  const float* Wr = (const float*)d_in[1];
  const float* br = (const float*)d_in[2];
  const float* W1 = (const float*)d_in[3];
  const float* b1 = (const float*)d_in[4];
  const float* ln1s = (const float*)d_in[5];
  const float* ln1b = (const float*)d_in[6];
  const float* W2 = (const float*)d_in[7];
  const float* b2 = (const float*)d_in[8];
  const float* ln2s = (const float*)d_in[9];
  const float* ln2b = (const float*)d_in[10];
  float* outb = (float*)d_out;

  if (ws_size >= (size_t)WS_ATOM) {
    char* ws = (char*)d_ws;
    u16* W1F = (u16*)(ws + MW_W1F);
    u16* W2F = (u16*)(ws + MW_W2F);
    uint4* recAll = (uint4*)(ws + MW_REC);
    uint2* pairRW = (uint2*)(ws + MW_PRW);
    int* cntE = (int*)(ws + MW_CNT);
    u32* blkCnt = (u32*)(ws + MW_BCNT);
    u32* blkBase = (u32*)(ws + MW_BBASE);
    uint2* idx = (uint2*)(ws + MW_IDX);

    k_router_f<<<256, 256, 0, stream>>>(x0, Wr, br, recAll);
    k_count<<<256, 256, 0, stream>>>(recAll, blkCnt);
    k_offset<<<1, 256, 0, stream>>>(blkCnt, blkBase, cntE);
    k_place<<<256, 256, 0, stream>>>(recAll, blkBase, idx, pairRW);
    if (ws_size >= (size_t)WS_FAST) {
      u16* ybuf = (u16*)(ws + MW_YBUF);
      k_pack<<<dim3(128, 8, 2), 64, 0, stream>>>(W1, W2, W1F, W2F);
      k_expert_g<<<dim3(256, 8), 512, 0, stream>>>(x0, W1F, b1, ln1s, ln1b, W2F, b2, ln2s, ln2b,
                                                   idx, cntE, ybuf);
      k_combine<<<16384, 256, 0, stream>>>(x0, pairRW, ybuf, outb);
    } else {
      u16* W1T = (u16*)(ws + MW_W1T);
      u16* W2T = (u16*)(ws + MW_W2T);
      k_transpose<<<dim3(64, 8, 2), 256, 0, stream>>>(W1, W2, W1T, W2T);
      hipMemsetAsync(d_out, 0, (size_t)NTOK * 256 * 4, stream);
      k_expert<<<dim3(256, 8), 512, 0, stream>>>(x0, W1T, b1, ln1s, ln1b, W2T, b2, ln2s, ln2b,
                                                 idx, cntE, outb);
      k_final<<<8192, 256, 0, stream>>>(x0, outb);
    }
  } else {
    k_router_fb<<<256, 256, 0, stream>>>(x0, Wr, br, outb);
    k_scan_fb<<<1, 1024, 0, stream>>>(outb);
    k_mlp_fb<<<NTOK, 256, 0, stream>>>(x0, W1, b1, ln1s, ln1b, W2, b2, ln2s, ln2b, outb);
  }
}